// Round 2
// baseline (542.908 us; speedup 1.0000x reference)
//
#include <hip/hip_runtime.h>
#include <hip/hip_bf16.h>
#include <stddef.h>

// Problem dims
#define BB 64
#define TTOT 64
#define EE 64
#define HH 128
#define G4 512          // 4*H
#define VIN 256
#define VOUT 32000

typedef __attribute__((ext_vector_type(8))) short bf16x8;
typedef __attribute__((ext_vector_type(4))) float f32x4;

__device__ __forceinline__ unsigned short f2bf(float x) {
    unsigned int u = __float_as_uint(x);
    unsigned int r = (u + 0x7fffu + ((u >> 16) & 1u)) >> 16;
    return (unsigned short)r;
}

__device__ __forceinline__ float fsig(float x) {
    return 1.f / (1.f + __expf(-x));
}
__device__ __forceinline__ float ftanh(float x) {
    // 1 - 2/(e^{2x}+1); saturates correctly at +/-1 for large |x|
    return 1.f - 2.f / (__expf(2.f * x) + 1.f);
}

// ---------------- fc_W fp32 -> bf16 ----------------
__global__ void conv_bf16(const float* __restrict__ in, unsigned short* __restrict__ out, int n) {
    for (int i = blockIdx.x * blockDim.x + threadIdx.x; i < n; i += gridDim.x * blockDim.x)
        out[i] = f2bf(in[i]);
}

// ---------------- encoder gate table: table[v][g] = emb[v]·Wih[g] + bih[g] ----------------
__global__ __launch_bounds__(512) void enc_table_k(const float* __restrict__ emb,
                                                   const float* __restrict__ Wih,
                                                   const float* __restrict__ bih,
                                                   float* __restrict__ table) {
    int v = blockIdx.x;
    int g = threadIdx.x;
    __shared__ __align__(16) float x[EE];
    if (g < EE) x[g] = (v == 0) ? 0.f : emb[(size_t)v * EE + g];
    __syncthreads();
    float acc = bih[g];
    const float* wr = Wih + (size_t)g * EE;
#pragma unroll
    for (int e = 0; e < EE; e += 4) {
        float4 w4 = *(const float4*)(wr + e);
        float4 x4 = *(const float4*)(&x[e]);
        acc = fmaf(x4.x, w4.x, acc);
        acc = fmaf(x4.y, w4.y, acc);
        acc = fmaf(x4.z, w4.z, acc);
        acc = fmaf(x4.w, w4.w, acc);
    }
    table[(size_t)v * G4 + g] = acc;
}

// ---------------- decoder input gates: xg[t*64+b][g] = dec_emb[tgt[b][t]]·Wih[g] + bih[g] ----------------
__global__ __launch_bounds__(512) void xg_dec_k(const int* __restrict__ tgt,
                                                const float* __restrict__ emb,
                                                const float* __restrict__ Wih,
                                                const float* __restrict__ bih,
                                                float* __restrict__ xg) {
    int p0 = blockIdx.x * 4;  // pair index = t*64 + b, t in [0,63)
    int g = threadIdx.x;
    __shared__ __align__(16) float x[4][EE];
    if (g < 4 * EE) {
        int pr = g >> 6, e = g & 63;
        int pair = p0 + pr;
        int t = pair >> 6, b = pair & 63;
        int tok = tgt[b * TTOT + t];
        x[pr][e] = (tok == 0) ? 0.f : emb[(size_t)tok * EE + e];
    }
    __syncthreads();
    float bi = bih[g];
    float acc0 = bi, acc1 = bi, acc2 = bi, acc3 = bi;
    const float* wr = Wih + (size_t)g * EE;
#pragma unroll
    for (int e = 0; e < EE; e += 4) {
        float4 w4 = *(const float4*)(wr + e);
#define STEP(pr, accv)                                        \
        {                                                     \
            float4 x4 = *(const float4*)(&x[pr][e]);          \
            accv = fmaf(x4.x, w4.x, accv);                    \
            accv = fmaf(x4.y, w4.y, accv);                    \
            accv = fmaf(x4.z, w4.z, accv);                    \
            accv = fmaf(x4.w, w4.w, accv);                    \
        }
        STEP(0, acc0) STEP(1, acc1) STEP(2, acc2) STEP(3, acc3)
#undef STEP
    }
    xg[(size_t)(p0 + 0) * G4 + g] = acc0;
    xg[(size_t)(p0 + 1) * G4 + g] = acc1;
    xg[(size_t)(p0 + 2) * G4 + g] = acc2;
    xg[(size_t)(p0 + 3) * G4 + g] = acc3;
}

// ---------------- encoder LSTM: one block per batch row ----------------
// 4 independent FMA chains via float4 lanes; next-step table value prefetched.
__global__ __launch_bounds__(512) void lstm_enc_k(const float* __restrict__ table,
                                                  const int* __restrict__ src,
                                                  const float* __restrict__ Whh,
                                                  const float* __restrict__ bhh,
                                                  float* __restrict__ hfin,
                                                  float* __restrict__ cfin) {
    int b = blockIdx.x, g = threadIdx.x;
    __shared__ __align__(16) float h[HH];
    __shared__ float gates[G4];
    __shared__ int toks[TTOT];

    float w[HH];
#pragma unroll
    for (int k = 0; k < HH; k += 4) {
        float4 t4 = *(const float4*)(Whh + (size_t)g * HH + k);
        w[k] = t4.x; w[k + 1] = t4.y; w[k + 2] = t4.z; w[k + 3] = t4.w;
    }
    if (g < TTOT) toks[g] = src[b * TTOT + g];
    if (g < HH) h[g] = 0.f;
    float c = 0.f;
    float bb = bhh[g];
    __syncthreads();

    float xv = table[(size_t)toks[0] * G4 + g];

#pragma unroll 1
    for (int t = 0; t < TTOT; ++t) {
        // prefetch next step's input-gate value (latency hides under the chain)
        float xn = (t + 1 < TTOT) ? table[(size_t)toks[t + 1] * G4 + g] : 0.f;
        float a0 = xv + bb, a1 = 0.f, a2 = 0.f, a3 = 0.f;
#pragma unroll
        for (int k = 0; k < HH; k += 4) {
            float4 h4 = *(const float4*)(&h[k]);
            a0 = fmaf(h4.x, w[k], a0);
            a1 = fmaf(h4.y, w[k + 1], a1);
            a2 = fmaf(h4.z, w[k + 2], a2);
            a3 = fmaf(h4.w, w[k + 3], a3);
        }
        gates[g] = (a0 + a1) + (a2 + a3);
        __syncthreads();
        if (g < HH) {
            float fi = fsig(gates[g]);
            float ff = fsig(gates[HH + g]);
            float fg = ftanh(gates[2 * HH + g]);
            float fo = fsig(gates[3 * HH + g]);
            c = ff * c + fi * fg;
            h[g] = fo * ftanh(c);
        }
        __syncthreads();
        xv = xn;
    }
    if (g < HH) {
        hfin[(size_t)b * HH + g] = h[g];
        cfin[(size_t)b * HH + g] = c;
    }
}

// ---------------- decoder LSTM: one block per batch row, writes hs as bf16 ----------------
__global__ __launch_bounds__(512) void lstm_dec_k(const float* __restrict__ xg,
                                                  const float* __restrict__ Whh,
                                                  const float* __restrict__ bhh,
                                                  const float* __restrict__ h0,
                                                  const float* __restrict__ c0,
                                                  unsigned short* __restrict__ hs) {
    int b = blockIdx.x, g = threadIdx.x;
    __shared__ __align__(16) float h[HH];
    __shared__ float gates[G4];

    float w[HH];
#pragma unroll
    for (int k = 0; k < HH; k += 4) {
        float4 t4 = *(const float4*)(Whh + (size_t)g * HH + k);
        w[k] = t4.x; w[k + 1] = t4.y; w[k + 2] = t4.z; w[k + 3] = t4.w;
    }
    float c = 0.f;
    if (g < HH) {
        h[g] = h0[(size_t)b * HH + g];
        c = c0[(size_t)b * HH + g];
    }
    float bb = bhh[g];
    __syncthreads();

    float xv = xg[(size_t)b * G4 + g];  // t=0 term

#pragma unroll 1
    for (int t = 0; t < TTOT - 1; ++t) {
        float xn = (t + 1 < TTOT - 1) ? xg[((size_t)(t + 1) * BB + b) * G4 + g] : 0.f;
        float a0 = xv + bb, a1 = 0.f, a2 = 0.f, a3 = 0.f;
#pragma unroll
        for (int k = 0; k < HH; k += 4) {
            float4 h4 = *(const float4*)(&h[k]);
            a0 = fmaf(h4.x, w[k], a0);
            a1 = fmaf(h4.y, w[k + 1], a1);
            a2 = fmaf(h4.z, w[k + 2], a2);
            a3 = fmaf(h4.w, w[k + 3], a3);
        }
        gates[g] = (a0 + a1) + (a2 + a3);
        __syncthreads();
        if (g < HH) {
            float fi = fsig(gates[g]);
            float ff = fsig(gates[HH + g]);
            float fg = ftanh(gates[2 * HH + g]);
            float fo = fsig(gates[3 * HH + g]);
            c = ff * c + fi * fg;
            float hn = fo * ftanh(c);
            h[g] = hn;
            hs[((size_t)t * BB + b) * HH + g] = f2bf(hn);
        }
        __syncthreads();
        xv = xn;
    }
}

// ---------------- zero out[:, 0, :] ----------------
__global__ void zero_t0_k(float* __restrict__ out) {
    int b = blockIdx.x;
    float4* p = (float4*)(out + (size_t)b * TTOT * VOUT);
    float4 z = make_float4(0.f, 0.f, 0.f, 0.f);
    for (int i = threadIdx.x; i < VOUT / 4; i += blockDim.x) p[i] = z;
}

// ---------------- FC head: out[b][t+1][n] = hs[t][b]·fc_W[n] + fc_b[n] ----------------
// Operand-swapped MFMA: A = fc_W tile (M = n), B = hs (N = batch row).
// D reg index j walks 4 consecutive n for one batch row -> float4 stores.
// grid (63, 250): x = t (fast -> concurrent blocks share fc_W band in L2), y = n-tile.
__global__ __launch_bounds__(256) void fc_k(const unsigned short* __restrict__ hs,
                                            const unsigned short* __restrict__ fw,
                                            const float* __restrict__ fb,
                                            float* __restrict__ out) {
    int t = blockIdx.x;
    int n0 = blockIdx.y * 128;
    int wave = threadIdx.x >> 6;   // wave covers batch rows [wave*16, wave*16+16)
    int lane = threadIdx.x & 63;
    int l15 = lane & 15;
    int kg = lane >> 4;            // k-group 0..3

    // B fragments (hs): B[N = l15 (batch row), K = kt*32 + kg*8 + j]
    const unsigned short* brow = hs + ((size_t)t * BB + wave * 16 + l15) * HH + kg * 8;
    bf16x8 b[4];
#pragma unroll
    for (int kt = 0; kt < 4; ++kt) b[kt] = *(const bf16x8*)(brow + kt * 32);

    size_t outbase = (size_t)(wave * 16 + l15) * TTOT * VOUT + (size_t)(t + 1) * VOUT;

#pragma unroll
    for (int nt = 0; nt < 8; ++nt) {
        // A fragments (fc_W): A[M = l15 (n), K = kt*32 + kg*8 + j]
        const unsigned short* arow = fw + (size_t)(n0 + nt * 16 + l15) * HH + kg * 8;
        f32x4 acc = (f32x4){0.f, 0.f, 0.f, 0.f};
#pragma unroll
        for (int kt = 0; kt < 4; ++kt) {
            bf16x8 a = *(const bf16x8*)(arow + kt * 32);
            acc = __builtin_amdgcn_mfma_f32_16x16x32_bf16(a, b[kt], acc, 0, 0, 0);
        }
        // D: lane holds n = n0 + nt*16 + kg*4 + j (j=0..3 consecutive), batch = wave*16 + l15
        int nc = n0 + nt * 16 + kg * 4;
        float4 bias = *(const float4*)(fb + nc);
        float4 v;
        v.x = acc[0] + bias.x;
        v.y = acc[1] + bias.y;
        v.z = acc[2] + bias.z;
        v.w = acc[3] + bias.w;
        *(float4*)(out + outbase + nc) = v;
    }
}

extern "C" void kernel_launch(void* const* d_in, const int* in_sizes, int n_in,
                              void* d_out, int out_size, void* d_ws, size_t ws_size,
                              hipStream_t stream) {
    const int* src = (const int*)d_in[0];
    const int* tgt = (const int*)d_in[1];
    const float* enc_emb = (const float*)d_in[2];
    const float* dec_emb = (const float*)d_in[3];
    const float* enc_Wih = (const float*)d_in[4];
    const float* enc_Whh = (const float*)d_in[5];
    const float* enc_bih = (const float*)d_in[6];
    const float* enc_bhh = (const float*)d_in[7];
    const float* dec_Wih = (const float*)d_in[8];
    const float* dec_Whh = (const float*)d_in[9];
    const float* dec_bih = (const float*)d_in[10];
    const float* dec_bhh = (const float*)d_in[11];
    const float* fc_W = (const float*)d_in[12];
    const float* fc_b = (const float*)d_in[13];
    float* out = (float*)d_out;
    char* ws = (char*)d_ws;

    // workspace layout (bytes)
    float* table = (float*)(ws + 0);                        // 256*512*4   = 524288
    float* hfin = (float*)(ws + 524288);                    // 64*128*4    = 32768
    float* cfin = (float*)(ws + 557056);                    // 64*128*4    = 32768
    unsigned short* hs = (unsigned short*)(ws + 589824);    // 63*64*128*2 = 1032192
    unsigned short* fwb = (unsigned short*)(ws + 1622016);  // 32000*128*2 = 8192000
    float* xgd = (float*)(ws + 9814016);                    // 63*64*512*4 = 8257536
    // total 18071552 bytes

    conv_bf16<<<2048, 256, 0, stream>>>(fc_W, fwb, VOUT * HH);
    enc_table_k<<<VIN, 512, 0, stream>>>(enc_emb, enc_Wih, enc_bih, table);
    xg_dec_k<<<(63 * 64) / 4, 512, 0, stream>>>(tgt, dec_emb, dec_Wih, dec_bih, xgd);
    lstm_enc_k<<<BB, 512, 0, stream>>>(table, src, enc_Whh, enc_bhh, hfin, cfin);
    lstm_dec_k<<<BB, 512, 0, stream>>>(xgd, dec_Whh, dec_bhh, hfin, cfin, hs);
    zero_t0_k<<<BB, 256, 0, stream>>>(out);
    fc_k<<<dim3(63, 250), 256, 0, stream>>>(hs, fwb, fc_b, out);
}

// Round 3
// 436.509 us; speedup vs baseline: 1.2437x; 1.2437x over previous
//
#include <hip/hip_runtime.h>
#include <hip/hip_bf16.h>
#include <stddef.h>

// Problem dims
#define BB 64
#define TTOT 64
#define EE 64
#define HH 128
#define G4 512          // 4*H
#define VIN 256
#define VOUT 32000

typedef __attribute__((ext_vector_type(8))) short bf16x8;
typedef __attribute__((ext_vector_type(4))) float f32x4;

__device__ __forceinline__ unsigned short f2bf(float x) {
    unsigned int u = __float_as_uint(x);
    unsigned int r = (u + 0x7fffu + ((u >> 16) & 1u)) >> 16;
    return (unsigned short)r;
}

__device__ __forceinline__ float fsig(float x) {
    return 1.f / (1.f + __expf(-x));
}
__device__ __forceinline__ float ftanh(float x) {
    // 1 - 2/(e^{2x}+1); saturates correctly at +/-1 for large |x|
    return 1.f - 2.f / (__expf(2.f * x) + 1.f);
}

// ---------------- fc_W fp32 -> bf16 ----------------
__global__ void conv_bf16(const float* __restrict__ in, unsigned short* __restrict__ out, int n) {
    for (int i = blockIdx.x * blockDim.x + threadIdx.x; i < n; i += gridDim.x * blockDim.x)
        out[i] = f2bf(in[i]);
}

// ---------------- encoder gate table: table[v][g] = emb[v]·Wih[g] + bih[g] ----------------
__global__ __launch_bounds__(512) void enc_table_k(const float* __restrict__ emb,
                                                   const float* __restrict__ Wih,
                                                   const float* __restrict__ bih,
                                                   float* __restrict__ table) {
    int v = blockIdx.x;
    int g = threadIdx.x;
    __shared__ __align__(16) float x[EE];
    if (g < EE) x[g] = (v == 0) ? 0.f : emb[(size_t)v * EE + g];
    __syncthreads();
    float acc = bih[g];
    const float* wr = Wih + (size_t)g * EE;
#pragma unroll
    for (int e = 0; e < EE; e += 4) {
        float4 w4 = *(const float4*)(wr + e);
        float4 x4 = *(const float4*)(&x[e]);
        acc = fmaf(x4.x, w4.x, acc);
        acc = fmaf(x4.y, w4.y, acc);
        acc = fmaf(x4.z, w4.z, acc);
        acc = fmaf(x4.w, w4.w, acc);
    }
    table[(size_t)v * G4 + g] = acc;
}

// ---------------- decoder input gates: xg[t*64+b][g] = dec_emb[tgt[b][t]]·Wih[g] + bih[g] ----------------
__global__ __launch_bounds__(512) void xg_dec_k(const int* __restrict__ tgt,
                                                const float* __restrict__ emb,
                                                const float* __restrict__ Wih,
                                                const float* __restrict__ bih,
                                                float* __restrict__ xg) {
    int p0 = blockIdx.x * 4;  // pair index = t*64 + b, t in [0,63)
    int g = threadIdx.x;
    __shared__ __align__(16) float x[4][EE];
    if (g < 4 * EE) {
        int pr = g >> 6, e = g & 63;
        int pair = p0 + pr;
        int t = pair >> 6, b = pair & 63;
        int tok = tgt[b * TTOT + t];
        x[pr][e] = (tok == 0) ? 0.f : emb[(size_t)tok * EE + e];
    }
    __syncthreads();
    float bi = bih[g];
    float acc0 = bi, acc1 = bi, acc2 = bi, acc3 = bi;
    const float* wr = Wih + (size_t)g * EE;
#pragma unroll
    for (int e = 0; e < EE; e += 4) {
        float4 w4 = *(const float4*)(wr + e);
#define STEP(pr, accv)                                        \
        {                                                     \
            float4 x4 = *(const float4*)(&x[pr][e]);          \
            accv = fmaf(x4.x, w4.x, accv);                    \
            accv = fmaf(x4.y, w4.y, accv);                    \
            accv = fmaf(x4.z, w4.z, accv);                    \
            accv = fmaf(x4.w, w4.w, accv);                    \
        }
        STEP(0, acc0) STEP(1, acc1) STEP(2, acc2) STEP(3, acc3)
#undef STEP
    }
    xg[(size_t)(p0 + 0) * G4 + g] = acc0;
    xg[(size_t)(p0 + 1) * G4 + g] = acc1;
    xg[(size_t)(p0 + 2) * G4 + g] = acc2;
    xg[(size_t)(p0 + 3) * G4 + g] = acc3;
}

// ---------------- encoder LSTM: one block per batch row ----------------
__global__ __launch_bounds__(512) void lstm_enc_k(const float* __restrict__ table,
                                                  const int* __restrict__ src,
                                                  const float* __restrict__ Whh,
                                                  const float* __restrict__ bhh,
                                                  float* __restrict__ hfin,
                                                  float* __restrict__ cfin) {
    int b = blockIdx.x, g = threadIdx.x;
    __shared__ __align__(16) float h[HH];
    __shared__ float gates[G4];
    __shared__ int toks[TTOT];

    float w[HH];
#pragma unroll
    for (int k = 0; k < HH; k += 4) {
        float4 t4 = *(const float4*)(Whh + (size_t)g * HH + k);
        w[k] = t4.x; w[k + 1] = t4.y; w[k + 2] = t4.z; w[k + 3] = t4.w;
    }
    if (g < TTOT) toks[g] = src[b * TTOT + g];
    if (g < HH) h[g] = 0.f;
    float c = 0.f;
    float bb = bhh[g];
    __syncthreads();

    float xv = table[(size_t)toks[0] * G4 + g];

#pragma unroll 1
    for (int t = 0; t < TTOT; ++t) {
        float xn = (t + 1 < TTOT) ? table[(size_t)toks[t + 1] * G4 + g] : 0.f;
        float a0 = xv + bb, a1 = 0.f, a2 = 0.f, a3 = 0.f;
#pragma unroll
        for (int k = 0; k < HH; k += 4) {
            float4 h4 = *(const float4*)(&h[k]);
            a0 = fmaf(h4.x, w[k], a0);
            a1 = fmaf(h4.y, w[k + 1], a1);
            a2 = fmaf(h4.z, w[k + 2], a2);
            a3 = fmaf(h4.w, w[k + 3], a3);
        }
        gates[g] = (a0 + a1) + (a2 + a3);
        __syncthreads();
        if (g < HH) {
            float fi = fsig(gates[g]);
            float ff = fsig(gates[HH + g]);
            float fg = ftanh(gates[2 * HH + g]);
            float fo = fsig(gates[3 * HH + g]);
            c = ff * c + fi * fg;
            h[g] = fo * ftanh(c);
        }
        __syncthreads();
        xv = xn;
    }
    if (g < HH) {
        hfin[(size_t)b * HH + g] = h[g];
        cfin[(size_t)b * HH + g] = c;
    }
}

// ---------------- decoder LSTM: one block per batch row, writes hs as bf16 ----------------
__global__ __launch_bounds__(512) void lstm_dec_k(const float* __restrict__ xg,
                                                  const float* __restrict__ Whh,
                                                  const float* __restrict__ bhh,
                                                  const float* __restrict__ h0,
                                                  const float* __restrict__ c0,
                                                  unsigned short* __restrict__ hs) {
    int b = blockIdx.x, g = threadIdx.x;
    __shared__ __align__(16) float h[HH];
    __shared__ float gates[G4];

    float w[HH];
#pragma unroll
    for (int k = 0; k < HH; k += 4) {
        float4 t4 = *(const float4*)(Whh + (size_t)g * HH + k);
        w[k] = t4.x; w[k + 1] = t4.y; w[k + 2] = t4.z; w[k + 3] = t4.w;
    }
    float c = 0.f;
    if (g < HH) {
        h[g] = h0[(size_t)b * HH + g];
        c = c0[(size_t)b * HH + g];
    }
    float bb = bhh[g];
    __syncthreads();

    float xv = xg[(size_t)b * G4 + g];  // t=0 term

#pragma unroll 1
    for (int t = 0; t < TTOT - 1; ++t) {
        float xn = (t + 1 < TTOT - 1) ? xg[((size_t)(t + 1) * BB + b) * G4 + g] : 0.f;
        float a0 = xv + bb, a1 = 0.f, a2 = 0.f, a3 = 0.f;
#pragma unroll
        for (int k = 0; k < HH; k += 4) {
            float4 h4 = *(const float4*)(&h[k]);
            a0 = fmaf(h4.x, w[k], a0);
            a1 = fmaf(h4.y, w[k + 1], a1);
            a2 = fmaf(h4.z, w[k + 2], a2);
            a3 = fmaf(h4.w, w[k + 3], a3);
        }
        gates[g] = (a0 + a1) + (a2 + a3);
        __syncthreads();
        if (g < HH) {
            float fi = fsig(gates[g]);
            float ff = fsig(gates[HH + g]);
            float fg = ftanh(gates[2 * HH + g]);
            float fo = fsig(gates[3 * HH + g]);
            c = ff * c + fi * fg;
            float hn = fo * ftanh(c);
            h[g] = hn;
            hs[((size_t)t * BB + b) * HH + g] = f2bf(hn);
        }
        __syncthreads();
        xv = xn;
    }
}

// ---------------- zero out[:, 0, :] ----------------
__global__ void zero_t0_k(float* __restrict__ out) {
    int b = blockIdx.x;
    float4* p = (float4*)(out + (size_t)b * TTOT * VOUT);
    float4 z = make_float4(0.f, 0.f, 0.f, 0.f);
    for (int i = threadIdx.x; i < VOUT / 4; i += blockDim.x) p[i] = z;
}

// ---------------- FC head, write-contiguity tiling ----------------
// One block = one batch row b  x  one n-band of 1600.
// N-operand = the 64 decoder steps of row b (4 subtiles of 16; t=63 masked).
// M-operand = fc_W rows (n). Each block writes 6.4KB contiguous per (b,t) row;
// consecutive block ids (same b, adjacent bands) complete full 128KB rows.
// grid = 64 * 20 = 1280, id = b*20 + band.
__global__ __launch_bounds__(256) void fc_k(const unsigned short* __restrict__ hs,
                                            const unsigned short* __restrict__ fw,
                                            const float* __restrict__ fb,
                                            float* __restrict__ out) {
    int id = blockIdx.x;
    int b = id / 20;
    int band = id % 20;
    int wave = threadIdx.x >> 6;
    int lane = threadIdx.x & 63;
    int l15 = lane & 15;
    int kg = lane >> 4;

    // B fragments (hs): 4 t-subtiles. B[N = t = ks*16+l15][K = kt*32 + kg*8 + j]
    bf16x8 bfr[4][4];
#pragma unroll
    for (int ks = 0; ks < 4; ++ks) {
        int t = ks * 16 + l15;
        int tc = t > 62 ? 62 : t;  // t=63 is masked at store; clamp load in-bounds
        const unsigned short* p = hs + ((size_t)tc * BB + b) * HH + kg * 8;
#pragma unroll
        for (int kt = 0; kt < 4; ++kt) bfr[ks][kt] = *(const bf16x8*)(p + kt * 32);
    }

    size_t outb = (size_t)b * TTOT * VOUT;

#pragma unroll 2
    for (int nt = 0; nt < 25; ++nt) {
        int n16 = band * 1600 + nt * 64 + wave * 16;  // this wave's 16-wide n subtile
        const unsigned short* arow = fw + (size_t)(n16 + l15) * HH + kg * 8;
        bf16x8 a[4];
#pragma unroll
        for (int kt = 0; kt < 4; ++kt) a[kt] = *(const bf16x8*)(arow + kt * 32);

        f32x4 ac0 = (f32x4){0.f, 0.f, 0.f, 0.f};
        f32x4 ac1 = (f32x4){0.f, 0.f, 0.f, 0.f};
        f32x4 ac2 = (f32x4){0.f, 0.f, 0.f, 0.f};
        f32x4 ac3 = (f32x4){0.f, 0.f, 0.f, 0.f};
#pragma unroll
        for (int kt = 0; kt < 4; ++kt) {
            ac0 = __builtin_amdgcn_mfma_f32_16x16x32_bf16(a[kt], bfr[0][kt], ac0, 0, 0, 0);
            ac1 = __builtin_amdgcn_mfma_f32_16x16x32_bf16(a[kt], bfr[1][kt], ac1, 0, 0, 0);
            ac2 = __builtin_amdgcn_mfma_f32_16x16x32_bf16(a[kt], bfr[2][kt], ac2, 0, 0, 0);
            ac3 = __builtin_amdgcn_mfma_f32_16x16x32_bf16(a[kt], bfr[3][kt], ac3, 0, 0, 0);
        }

        // D: lane l15 -> t (N), regs j -> 4 consecutive n (M) at kg*4
        int nc = n16 + kg * 4;
        float4 bias = *(const float4*)(fb + nc);
#define STORE(ks, accv)                                                     \
        {                                                                   \
            int t = ks * 16 + l15;                                          \
            if (t < 63) {                                                   \
                float4 v;                                                   \
                v.x = accv[0] + bias.x;                                     \
                v.y = accv[1] + bias.y;                                     \
                v.z = accv[2] + bias.z;                                     \
                v.w = accv[3] + bias.w;                                     \
                *(float4*)(out + outb + (size_t)(t + 1) * VOUT + nc) = v;   \
            }                                                               \
        }
        STORE(0, ac0) STORE(1, ac1) STORE(2, ac2) STORE(3, ac3)
#undef STORE
    }
}

extern "C" void kernel_launch(void* const* d_in, const int* in_sizes, int n_in,
                              void* d_out, int out_size, void* d_ws, size_t ws_size,
                              hipStream_t stream) {
    const int* src = (const int*)d_in[0];
    const int* tgt = (const int*)d_in[1];
    const float* enc_emb = (const float*)d_in[2];
    const float* dec_emb = (const float*)d_in[3];
    const float* enc_Wih = (const float*)d_in[4];
    const float* enc_Whh = (const float*)d_in[5];
    const float* enc_bih = (const float*)d_in[6];
    const float* enc_bhh = (const float*)d_in[7];
    const float* dec_Wih = (const float*)d_in[8];
    const float* dec_Whh = (const float*)d_in[9];
    const float* dec_bih = (const float*)d_in[10];
    const float* dec_bhh = (const float*)d_in[11];
    const float* fc_W = (const float*)d_in[12];
    const float* fc_b = (const float*)d_in[13];
    float* out = (float*)d_out;
    char* ws = (char*)d_ws;

    // workspace layout (bytes)
    float* table = (float*)(ws + 0);                        // 256*512*4   = 524288
    float* hfin = (float*)(ws + 524288);                    // 64*128*4    = 32768
    float* cfin = (float*)(ws + 557056);                    // 64*128*4    = 32768
    unsigned short* hs = (unsigned short*)(ws + 589824);    // 63*64*128*2 = 1032192
    unsigned short* fwb = (unsigned short*)(ws + 1622016);  // 32000*128*2 = 8192000
    float* xgd = (float*)(ws + 9814016);                    // 63*64*512*4 = 8257536
    // total 18071552 bytes

    conv_bf16<<<2048, 256, 0, stream>>>(fc_W, fwb, VOUT * HH);
    enc_table_k<<<VIN, 512, 0, stream>>>(enc_emb, enc_Wih, enc_bih, table);
    xg_dec_k<<<(63 * 64) / 4, 512, 0, stream>>>(tgt, dec_emb, dec_Wih, dec_bih, xgd);
    lstm_enc_k<<<BB, 512, 0, stream>>>(table, src, enc_Whh, enc_bhh, hfin, cfin);
    lstm_dec_k<<<BB, 512, 0, stream>>>(xgd, dec_Whh, dec_bhh, hfin, cfin, hs);
    zero_t0_k<<<BB, 256, 0, stream>>>(out);
    fc_k<<<1280, 256, 0, stream>>>(hs, fwb, fc_b, out);
}

// Round 4
// 359.941 us; speedup vs baseline: 1.5083x; 1.2127x over previous
//
#include <hip/hip_runtime.h>
#include <hip/hip_bf16.h>
#include <stddef.h>

// Problem dims
#define BB 64
#define TTOT 64
#define EE 64
#define HH 128
#define G4 512          // 4*H
#define VIN 256
#define VOUT 32000

typedef __attribute__((ext_vector_type(8))) short bf16x8;
typedef __attribute__((ext_vector_type(4))) float f32x4;

__device__ __forceinline__ unsigned short f2bf(float x) {
    unsigned int u = __float_as_uint(x);
    unsigned int r = (u + 0x7fffu + ((u >> 16) & 1u)) >> 16;
    return (unsigned short)r;
}

__device__ __forceinline__ float fsig(float x) {
    return 1.f / (1.f + __expf(-x));
}
__device__ __forceinline__ float ftanh(float x) {
    return 1.f - 2.f / (__expf(2.f * x) + 1.f);
}

// LDS h layout: pad 8 dwords every 32 so the four 32-float quarters start in
// different bank groups: idx(u) = u + (u>>5)*8  (quarter p base = p*40 dwords)
__device__ __forceinline__ int hidx(int u) { return u + (u >> 5) * 8; }
#define HPAD 152

// ---------------- fc_W fp32 -> bf16 ----------------
__global__ void conv_bf16(const float* __restrict__ in, unsigned short* __restrict__ out, int n) {
    for (int i = blockIdx.x * blockDim.x + threadIdx.x; i < n; i += gridDim.x * blockDim.x)
        out[i] = f2bf(in[i]);
}

// ---------------- encoder gate table: table[v][g] = emb[v]·Wih[g] + bih[g] ----------------
__global__ __launch_bounds__(512) void enc_table_k(const float* __restrict__ emb,
                                                   const float* __restrict__ Wih,
                                                   const float* __restrict__ bih,
                                                   float* __restrict__ table) {
    int v = blockIdx.x;
    int g = threadIdx.x;
    __shared__ __align__(16) float x[EE];
    if (g < EE) x[g] = (v == 0) ? 0.f : emb[(size_t)v * EE + g];
    __syncthreads();
    float acc = bih[g];
    const float* wr = Wih + (size_t)g * EE;
#pragma unroll
    for (int e = 0; e < EE; e += 4) {
        float4 w4 = *(const float4*)(wr + e);
        float4 x4 = *(const float4*)(&x[e]);
        acc = fmaf(x4.x, w4.x, acc);
        acc = fmaf(x4.y, w4.y, acc);
        acc = fmaf(x4.z, w4.z, acc);
        acc = fmaf(x4.w, w4.w, acc);
    }
    table[(size_t)v * G4 + g] = acc;
}

// ---------------- decoder input gates ----------------
__global__ __launch_bounds__(512) void xg_dec_k(const int* __restrict__ tgt,
                                                const float* __restrict__ emb,
                                                const float* __restrict__ Wih,
                                                const float* __restrict__ bih,
                                                float* __restrict__ xg) {
    int p0 = blockIdx.x * 4;  // pair index = t*64 + b, t in [0,63)
    int g = threadIdx.x;
    __shared__ __align__(16) float x[4][EE];
    if (g < 4 * EE) {
        int pr = g >> 6, e = g & 63;
        int pair = p0 + pr;
        int t = pair >> 6, b = pair & 63;
        int tok = tgt[b * TTOT + t];
        x[pr][e] = (tok == 0) ? 0.f : emb[(size_t)tok * EE + e];
    }
    __syncthreads();
    float bi = bih[g];
    float acc0 = bi, acc1 = bi, acc2 = bi, acc3 = bi;
    const float* wr = Wih + (size_t)g * EE;
#pragma unroll
    for (int e = 0; e < EE; e += 4) {
        float4 w4 = *(const float4*)(wr + e);
#define STEP(pr, accv)                                        \
        {                                                     \
            float4 x4 = *(const float4*)(&x[pr][e]);          \
            accv = fmaf(x4.x, w4.x, accv);                    \
            accv = fmaf(x4.y, w4.y, accv);                    \
            accv = fmaf(x4.z, w4.z, accv);                    \
            accv = fmaf(x4.w, w4.w, accv);                    \
        }
        STEP(0, acc0) STEP(1, acc1) STEP(2, acc2) STEP(3, acc3)
#undef STEP
    }
    xg[(size_t)(p0 + 0) * G4 + g] = acc0;
    xg[(size_t)(p0 + 1) * G4 + g] = acc1;
    xg[(size_t)(p0 + 2) * G4 + g] = acc2;
    xg[(size_t)(p0 + 3) * G4 + g] = acc3;
}

// ---------------- LSTM, quad-split structure ----------------
// thread = (u = tid>>2, p = tid&3). Lane p covers k in [32p, 32p+32) of the
// h-dot for ALL 4 gates (8 ds_read_b128/step). Quad shfl_xor reduce yields all
// 4 full gates per lane; x-gate + bhh injected pre-reduce in lane p==q.
// h double-buffered in LDS -> one barrier per step. c carried redundantly.
__global__ __launch_bounds__(512) void lstm_enc_k(const float* __restrict__ table,
                                                  const int* __restrict__ src,
                                                  const float* __restrict__ Whh,
                                                  const float* __restrict__ bhh,
                                                  float* __restrict__ hfin,
                                                  float* __restrict__ cfin) {
    int b = blockIdx.x;
    int tid = threadIdx.x;
    int u = tid >> 2, p = tid & 3;
    __shared__ __align__(16) float hbuf[2][HPAD];
    __shared__ int toks[TTOT];

    // weights: w[q][kk] = Whh[(q*128+u)][p*32+kk]
    float w[4][32];
#pragma unroll
    for (int q = 0; q < 4; ++q) {
        const float* wr = Whh + (size_t)(q * HH + u) * HH + p * 32;
#pragma unroll
        for (int kk = 0; kk < 32; kk += 4) {
            float4 t4 = *(const float4*)(wr + kk);
            w[q][kk] = t4.x; w[q][kk + 1] = t4.y; w[q][kk + 2] = t4.z; w[q][kk + 3] = t4.w;
        }
    }
    if (tid < TTOT) toks[tid] = src[b * TTOT + tid];
    if (p == 0) hbuf[0][hidx(u)] = 0.f;
    float bb = bhh[p * HH + u];
    float c = 0.f;
    __syncthreads();

    float xv = table[(size_t)toks[0] * G4 + p * HH + u];

#pragma unroll 1
    for (int t = 0; t < TTOT; ++t) {
        float xn = (t + 1 < TTOT) ? table[(size_t)toks[t + 1] * G4 + p * HH + u] : 0.f;
        const float* hq = &hbuf[t & 1][p * 40];
        float4 h4[8];
#pragma unroll
        for (int j = 0; j < 8; ++j) h4[j] = *(const float4*)(hq + j * 4);

        float v0 = (p == 0) ? (xv + bb) : 0.f;
        float v1 = (p == 1) ? (xv + bb) : 0.f;
        float v2 = (p == 2) ? (xv + bb) : 0.f;
        float v3 = (p == 3) ? (xv + bb) : 0.f;
#pragma unroll
        for (int j = 0; j < 8; ++j) {
            float4 h = h4[j];
#define FMA4(hc, kk)                              \
            v0 = fmaf(hc, w[0][kk], v0);          \
            v1 = fmaf(hc, w[1][kk], v1);          \
            v2 = fmaf(hc, w[2][kk], v2);          \
            v3 = fmaf(hc, w[3][kk], v3);
            FMA4(h.x, j * 4 + 0) FMA4(h.y, j * 4 + 1) FMA4(h.z, j * 4 + 2) FMA4(h.w, j * 4 + 3)
#undef FMA4
        }
        v0 += __shfl_xor(v0, 1); v1 += __shfl_xor(v1, 1); v2 += __shfl_xor(v2, 1); v3 += __shfl_xor(v3, 1);
        v0 += __shfl_xor(v0, 2); v1 += __shfl_xor(v1, 2); v2 += __shfl_xor(v2, 2); v3 += __shfl_xor(v3, 2);

        float fi = fsig(v0), ff = fsig(v1), fg = ftanh(v2), fo = fsig(v3);
        c = ff * c + fi * fg;
        float hn = fo * ftanh(c);
        if (p == 0) hbuf[(t + 1) & 1][hidx(u)] = hn;
        __syncthreads();
        xv = xn;
        if (t == TTOT - 1 && p == 0) {
            hfin[(size_t)b * HH + u] = hn;
            cfin[(size_t)b * HH + u] = c;
        }
    }
}

__global__ __launch_bounds__(512) void lstm_dec_k(const float* __restrict__ xg,
                                                  const float* __restrict__ Whh,
                                                  const float* __restrict__ bhh,
                                                  const float* __restrict__ h0,
                                                  const float* __restrict__ c0,
                                                  unsigned short* __restrict__ hs) {
    int b = blockIdx.x;
    int tid = threadIdx.x;
    int u = tid >> 2, p = tid & 3;
    __shared__ __align__(16) float hbuf[2][HPAD];

    float w[4][32];
#pragma unroll
    for (int q = 0; q < 4; ++q) {
        const float* wr = Whh + (size_t)(q * HH + u) * HH + p * 32;
#pragma unroll
        for (int kk = 0; kk < 32; kk += 4) {
            float4 t4 = *(const float4*)(wr + kk);
            w[q][kk] = t4.x; w[q][kk + 1] = t4.y; w[q][kk + 2] = t4.z; w[q][kk + 3] = t4.w;
        }
    }
    if (p == 0) hbuf[0][hidx(u)] = h0[(size_t)b * HH + u];
    float c = c0[(size_t)b * HH + u];
    float bb = bhh[p * HH + u];
    __syncthreads();

    float xv = xg[(size_t)b * G4 + p * HH + u];  // t=0 (pair = 0*64 + b)

#pragma unroll 1
    for (int t = 0; t < TTOT - 1; ++t) {
        float xn = (t + 1 < TTOT - 1) ? xg[((size_t)(t + 1) * BB + b) * G4 + p * HH + u] : 0.f;
        const float* hq = &hbuf[t & 1][p * 40];
        float4 h4[8];
#pragma unroll
        for (int j = 0; j < 8; ++j) h4[j] = *(const float4*)(hq + j * 4);

        float v0 = (p == 0) ? (xv + bb) : 0.f;
        float v1 = (p == 1) ? (xv + bb) : 0.f;
        float v2 = (p == 2) ? (xv + bb) : 0.f;
        float v3 = (p == 3) ? (xv + bb) : 0.f;
#pragma unroll
        for (int j = 0; j < 8; ++j) {
            float4 h = h4[j];
#define FMA4(hc, kk)                              \
            v0 = fmaf(hc, w[0][kk], v0);          \
            v1 = fmaf(hc, w[1][kk], v1);          \
            v2 = fmaf(hc, w[2][kk], v2);          \
            v3 = fmaf(hc, w[3][kk], v3);
            FMA4(h.x, j * 4 + 0) FMA4(h.y, j * 4 + 1) FMA4(h.z, j * 4 + 2) FMA4(h.w, j * 4 + 3)
#undef FMA4
        }
        v0 += __shfl_xor(v0, 1); v1 += __shfl_xor(v1, 1); v2 += __shfl_xor(v2, 1); v3 += __shfl_xor(v3, 1);
        v0 += __shfl_xor(v0, 2); v1 += __shfl_xor(v1, 2); v2 += __shfl_xor(v2, 2); v3 += __shfl_xor(v3, 2);

        float fi = fsig(v0), ff = fsig(v1), fg = ftanh(v2), fo = fsig(v3);
        c = ff * c + fi * fg;
        float hn = fo * ftanh(c);
        if (p == 0) {
            hbuf[(t + 1) & 1][hidx(u)] = hn;
            hs[((size_t)t * BB + b) * HH + u] = f2bf(hn);
        }
        __syncthreads();
        xv = xn;
    }
}

// ---------------- FC head, LDS-transposed contiguous-row stores ----------------
// block = (b, 256-wide n band); grid id = b*125 + nb so resident blocks
// concentrate in ~10 consecutive b slabs (write locality). Tile staged in LDS,
// then each wave stores 16 rows as full 1KB contiguous dwordx4 wave-stores.
// t=0 zero row fused (wave 0, r=0).
#define LDSW 260  // 256 + 4 pad dwords
__global__ __launch_bounds__(256) void fc_k(const unsigned short* __restrict__ hs,
                                            const unsigned short* __restrict__ fw,
                                            const float* __restrict__ fb,
                                            float* __restrict__ out) {
    int id = blockIdx.x;
    int b = id / 125;
    int nb = id % 125;
    int n0 = nb * 256;
    int wave = threadIdx.x >> 6;
    int lane = threadIdx.x & 63;
    int l15 = lane & 15;
    int kg = lane >> 4;

    __shared__ __align__(16) float lds[64 * LDSW];

    // B fragments (hs row b): B[N = t = ts*16+l15][K = kt*32 + kg*8 + j]
    bf16x8 bfr[4][4];
#pragma unroll
    for (int ts = 0; ts < 4; ++ts) {
        int t = ts * 16 + l15;
        int tc = t > 62 ? 62 : t;  // row 63 garbage, never stored
        const unsigned short* ph = hs + ((size_t)tc * BB + b) * HH + kg * 8;
#pragma unroll
        for (int kt = 0; kt < 4; ++kt) bfr[ts][kt] = *(const bf16x8*)(ph + kt * 32);
    }

    // compute 4 n-subtiles (ns) x 4 t-subtiles per wave, dump to LDS
#pragma unroll
    for (int i = 0; i < 4; ++i) {
        int ns = wave * 4 + i;                       // n subtile 0..15
        const unsigned short* arow = fw + (size_t)(n0 + ns * 16 + l15) * HH + kg * 8;
        bf16x8 a[4];
#pragma unroll
        for (int kt = 0; kt < 4; ++kt) a[kt] = *(const bf16x8*)(arow + kt * 32);

        f32x4 ac0 = (f32x4){0.f, 0.f, 0.f, 0.f};
        f32x4 ac1 = (f32x4){0.f, 0.f, 0.f, 0.f};
        f32x4 ac2 = (f32x4){0.f, 0.f, 0.f, 0.f};
        f32x4 ac3 = (f32x4){0.f, 0.f, 0.f, 0.f};
#pragma unroll
        for (int kt = 0; kt < 4; ++kt) {
            ac0 = __builtin_amdgcn_mfma_f32_16x16x32_bf16(a[kt], bfr[0][kt], ac0, 0, 0, 0);
            ac1 = __builtin_amdgcn_mfma_f32_16x16x32_bf16(a[kt], bfr[1][kt], ac1, 0, 0, 0);
            ac2 = __builtin_amdgcn_mfma_f32_16x16x32_bf16(a[kt], bfr[2][kt], ac2, 0, 0, 0);
            ac3 = __builtin_amdgcn_mfma_f32_16x16x32_bf16(a[kt], bfr[3][kt], ac3, 0, 0, 0);
        }
        // D: lane l15 -> t (N), regs j -> n offset kg*4+j (M)
        int nc = ns * 16 + kg * 4;
#define DUMP(ts, accv)                                                         \
        *(f32x4*)(&lds[(ts * 16 + l15) * LDSW + nc]) = accv;
        DUMP(0, ac0) DUMP(1, ac1) DUMP(2, ac2) DUMP(3, ac3)
#undef DUMP
    }
    __syncthreads();

    // store phase: wave w -> out rows t = w*16 .. w*16+15, 1KB contiguous each
    float4 bias = *(const float4*)(fb + n0 + lane * 4);
    size_t outb = (size_t)b * TTOT * VOUT + n0 + lane * 4;
#pragma unroll
    for (int r = 0; r < 16; ++r) {
        int ot = wave * 16 + r;
        float4 v;
        if (ot == 0) {
            v = make_float4(0.f, 0.f, 0.f, 0.f);
        } else {
            float4 s = *(const float4*)(&lds[(ot - 1) * LDSW + lane * 4]);
            v.x = s.x + bias.x; v.y = s.y + bias.y; v.z = s.z + bias.z; v.w = s.w + bias.w;
        }
        *(float4*)(out + outb + (size_t)ot * VOUT) = v;
    }
}

extern "C" void kernel_launch(void* const* d_in, const int* in_sizes, int n_in,
                              void* d_out, int out_size, void* d_ws, size_t ws_size,
                              hipStream_t stream) {
    const int* src = (const int*)d_in[0];
    const int* tgt = (const int*)d_in[1];
    const float* enc_emb = (const float*)d_in[2];
    const float* dec_emb = (const float*)d_in[3];
    const float* enc_Wih = (const float*)d_in[4];
    const float* enc_Whh = (const float*)d_in[5];
    const float* enc_bih = (const float*)d_in[6];
    const float* enc_bhh = (const float*)d_in[7];
    const float* dec_Wih = (const float*)d_in[8];
    const float* dec_Whh = (const float*)d_in[9];
    const float* dec_bih = (const float*)d_in[10];
    const float* dec_bhh = (const float*)d_in[11];
    const float* fc_W = (const float*)d_in[12];
    const float* fc_b = (const float*)d_in[13];
    float* out = (float*)d_out;
    char* ws = (char*)d_ws;

    // workspace layout (bytes)
    float* table = (float*)(ws + 0);                        // 256*512*4   = 524288
    float* hfin = (float*)(ws + 524288);                    // 64*128*4    = 32768
    float* cfin = (float*)(ws + 557056);                    // 64*128*4    = 32768
    unsigned short* hs = (unsigned short*)(ws + 589824);    // 63*64*128*2 = 1032192
    unsigned short* fwb = (unsigned short*)(ws + 1622016);  // 32000*128*2 = 8192000
    float* xgd = (float*)(ws + 9814016);                    // 63*64*512*4 = 8257536
    // total 18071552 bytes

    conv_bf16<<<2048, 256, 0, stream>>>(fc_W, fwb, VOUT * HH);
    enc_table_k<<<VIN, 512, 0, stream>>>(enc_emb, enc_Wih, enc_bih, table);
    xg_dec_k<<<(63 * 64) / 4, 512, 0, stream>>>(tgt, dec_emb, dec_Wih, dec_bih, xgd);
    lstm_enc_k<<<BB, 512, 0, stream>>>(table, src, enc_Whh, enc_bhh, hfin, cfin);
    lstm_dec_k<<<BB, 512, 0, stream>>>(xgd, dec_Whh, dec_bhh, hfin, cfin, hs);
    fc_k<<<64 * 125, 256, 0, stream>>>(hs, fwb, fc_b, out);
}

// Round 6
// 344.612 us; speedup vs baseline: 1.5754x; 1.0445x over previous
//
#include <hip/hip_runtime.h>
#include <hip/hip_bf16.h>
#include <stddef.h>

// Problem dims
#define BB 64
#define TTOT 64
#define EE 64
#define HH 128
#define G4 512          // 4*H
#define VIN 256
#define VOUT 32000

typedef __attribute__((ext_vector_type(8))) short bf16x8;
typedef __attribute__((ext_vector_type(4))) float f32x4;

__device__ __forceinline__ unsigned short f2bf(float x) {
    unsigned int u = __float_as_uint(x);
    unsigned int r = (u + 0x7fffu + ((u >> 16) & 1u)) >> 16;
    return (unsigned short)r;
}

__device__ __forceinline__ float fsig(float x) {
    return 1.f / (1.f + __expf(-x));
}
__device__ __forceinline__ float ftanh(float x) {
    return 1.f - 2.f / (__expf(2.f * x) + 1.f);
}

// quad (4-lane) butterfly sum via DPP quad_perm — pure VALU, no DS ops.
__device__ __forceinline__ float quad_sum(float v) {
    v += __int_as_float(__builtin_amdgcn_mov_dpp(__float_as_int(v), 0xB1, 0xF, 0xF, true));  // xor 1
    v += __int_as_float(__builtin_amdgcn_mov_dpp(__float_as_int(v), 0x4E, 0xF, 0xF, true));  // xor 2
    return v;
}

// LDS h layout: pad 8 dwords every 32 so the four 32-float quarters start in
// different bank groups: idx(u) = u + (u>>5)*8  (quarter p base = p*40 dwords)
__device__ __forceinline__ int hidx(int u) { return u + (u >> 5) * 8; }
#define HPAD 152

// ---------------- fc_W fp32 -> bf16 (vectorized) ----------------
__global__ void conv_bf16(const float* __restrict__ in, unsigned short* __restrict__ out, int n4) {
    int i = blockIdx.x * blockDim.x + threadIdx.x;
    if (i < n4) {
        float4 v = *(const float4*)(in + i * 4);
        ushort4 o;
        o.x = f2bf(v.x); o.y = f2bf(v.y); o.z = f2bf(v.z); o.w = f2bf(v.w);
        *(ushort4*)(out + i * 4) = o;
    }
}

// ---------------- encoder gate table: table[v][g] = emb[v]·Wih[g] + bih[g] ----------------
__global__ __launch_bounds__(512) void enc_table_k(const float* __restrict__ emb,
                                                   const float* __restrict__ Wih,
                                                   const float* __restrict__ bih,
                                                   float* __restrict__ table) {
    int v = blockIdx.x;
    int g = threadIdx.x;
    __shared__ __align__(16) float x[EE];
    if (g < EE) x[g] = (v == 0) ? 0.f : emb[(size_t)v * EE + g];
    __syncthreads();
    float acc = bih[g];
    const float* wr = Wih + (size_t)g * EE;
#pragma unroll
    for (int e = 0; e < EE; e += 4) {
        float4 w4 = *(const float4*)(wr + e);
        float4 x4 = *(const float4*)(&x[e]);
        acc = fmaf(x4.x, w4.x, acc);
        acc = fmaf(x4.y, w4.y, acc);
        acc = fmaf(x4.z, w4.z, acc);
        acc = fmaf(x4.w, w4.w, acc);
    }
    table[(size_t)v * G4 + g] = acc;
}

// ---------------- decoder input gates, 8 (t,b) pairs per block ----------------
__global__ __launch_bounds__(512) void xg_dec_k(const int* __restrict__ tgt,
                                                const float* __restrict__ emb,
                                                const float* __restrict__ Wih,
                                                const float* __restrict__ bih,
                                                float* __restrict__ xg) {
    int p0 = blockIdx.x * 8;  // pair index = t*64 + b, t in [0,63)
    int g = threadIdx.x;
    __shared__ __align__(16) float x[8][EE];
    {
        int pr = g >> 6, e = g & 63;
        int pair = p0 + pr;
        int t = pair >> 6, b = pair & 63;
        int tok = tgt[b * TTOT + t];
        x[pr][e] = (tok == 0) ? 0.f : emb[(size_t)tok * EE + e];
    }
    __syncthreads();
    float bi = bih[g];
    float acc[8];
#pragma unroll
    for (int pr = 0; pr < 8; ++pr) acc[pr] = bi;
    const float* wr = Wih + (size_t)g * EE;
#pragma unroll
    for (int e = 0; e < EE; e += 4) {
        float4 w4 = *(const float4*)(wr + e);
#pragma unroll
        for (int pr = 0; pr < 8; ++pr) {
            float4 x4 = *(const float4*)(&x[pr][e]);
            acc[pr] = fmaf(x4.x, w4.x, acc[pr]);
            acc[pr] = fmaf(x4.y, w4.y, acc[pr]);
            acc[pr] = fmaf(x4.z, w4.z, acc[pr]);
            acc[pr] = fmaf(x4.w, w4.w, acc[pr]);
        }
    }
#pragma unroll
    for (int pr = 0; pr < 8; ++pr)
        xg[(size_t)(p0 + pr) * G4 + g] = acc[pr];
}

// ---------------- fused encoder+decoder LSTM: one block per batch row ----------------
// thread = (u = tid>>2, p = tid&3). Lane p covers k in [32p,32p+32) of the
// h-dot for ALL 4 gates (8 ds_read_b128/step); DPP quad butterfly gives each
// lane all 4 full gates in-register (no DS on the reduce). h double-buffered,
// one barrier per step. Decoder continues in the same block: Whh/bhh reloaded,
// h/c stay in place.
__global__ __launch_bounds__(512) void lstm_k(const float* __restrict__ table,
                                              const int* __restrict__ src,
                                              const float* __restrict__ eWhh,
                                              const float* __restrict__ ebhh,
                                              const float* __restrict__ xg,
                                              const float* __restrict__ dWhh,
                                              const float* __restrict__ dbhh,
                                              unsigned short* __restrict__ hs) {
    int b = blockIdx.x;
    int tid = threadIdx.x;
    int u = tid >> 2, p = tid & 3;
    __shared__ __align__(16) float hbuf[2][HPAD];
    __shared__ int toks[TTOT];

    // encoder weights: w[q][kk] = Whh[(q*128+u)][p*32+kk]
    float w[4][32];
#pragma unroll
    for (int q = 0; q < 4; ++q) {
        const float* wr = eWhh + (size_t)(q * HH + u) * HH + p * 32;
#pragma unroll
        for (int kk = 0; kk < 32; kk += 4) {
            float4 t4 = *(const float4*)(wr + kk);
            w[q][kk] = t4.x; w[q][kk + 1] = t4.y; w[q][kk + 2] = t4.z; w[q][kk + 3] = t4.w;
        }
    }
    if (tid < TTOT) toks[tid] = src[b * TTOT + tid];
    if (p == 0) hbuf[0][hidx(u)] = 0.f;
    float bb = ebhh[p * HH + u];
    float c = 0.f;
    __syncthreads();

    float xv = table[(size_t)toks[0] * G4 + p * HH + u];

    // ---- encoder: 64 steps ----
#pragma unroll 1
    for (int t = 0; t < TTOT; ++t) {
        float xn = (t + 1 < TTOT) ? table[(size_t)toks[t + 1] * G4 + p * HH + u] : 0.f;
        const float* hq = &hbuf[t & 1][p * 40];
        float4 h4[8];
#pragma unroll
        for (int j = 0; j < 8; ++j) h4[j] = *(const float4*)(hq + j * 4);

        float v0 = (p == 0) ? (xv + bb) : 0.f;
        float v1 = (p == 1) ? (xv + bb) : 0.f;
        float v2 = (p == 2) ? (xv + bb) : 0.f;
        float v3 = (p == 3) ? (xv + bb) : 0.f;
#pragma unroll
        for (int j = 0; j < 8; ++j) {
            float4 h = h4[j];
#define FMA4(hc, kk)                              \
            v0 = fmaf(hc, w[0][kk], v0);          \
            v1 = fmaf(hc, w[1][kk], v1);          \
            v2 = fmaf(hc, w[2][kk], v2);          \
            v3 = fmaf(hc, w[3][kk], v3);
            FMA4(h.x, j * 4 + 0) FMA4(h.y, j * 4 + 1) FMA4(h.z, j * 4 + 2) FMA4(h.w, j * 4 + 3)
#undef FMA4
        }
        v0 = quad_sum(v0); v1 = quad_sum(v1); v2 = quad_sum(v2); v3 = quad_sum(v3);

        float fi = fsig(v0), ff = fsig(v1), fg = ftanh(v2), fo = fsig(v3);
        c = ff * c + fi * fg;
        float hn = fo * ftanh(c);
        if (p == 0) hbuf[(t + 1) & 1][hidx(u)] = hn;
        __syncthreads();
        xv = xn;
    }

    // ---- switch to decoder weights; h/c stay ----
#pragma unroll
    for (int q = 0; q < 4; ++q) {
        const float* wr = dWhh + (size_t)(q * HH + u) * HH + p * 32;
#pragma unroll
        for (int kk = 0; kk < 32; kk += 4) {
            float4 t4 = *(const float4*)(wr + kk);
            w[q][kk] = t4.x; w[q][kk + 1] = t4.y; w[q][kk + 2] = t4.z; w[q][kk + 3] = t4.w;
        }
    }
    bb = dbhh[p * HH + u];
    xv = xg[(size_t)b * G4 + p * HH + u];  // t=0 (pair = 0*64 + b)

    // ---- decoder: 63 steps; enc ended with h in hbuf[0] (64 even) ----
#pragma unroll 1
    for (int t = 0; t < TTOT - 1; ++t) {
        float xn = (t + 1 < TTOT - 1) ? xg[((size_t)(t + 1) * BB + b) * G4 + p * HH + u] : 0.f;
        const float* hq = &hbuf[t & 1][p * 40];
        float4 h4[8];
#pragma unroll
        for (int j = 0; j < 8; ++j) h4[j] = *(const float4*)(hq + j * 4);

        float v0 = (p == 0) ? (xv + bb) : 0.f;
        float v1 = (p == 1) ? (xv + bb) : 0.f;
        float v2 = (p == 2) ? (xv + bb) : 0.f;
        float v3 = (p == 3) ? (xv + bb) : 0.f;
#pragma unroll
        for (int j = 0; j < 8; ++j) {
            float4 h = h4[j];
#define FMA4(hc, kk)                              \
            v0 = fmaf(hc, w[0][kk], v0);          \
            v1 = fmaf(hc, w[1][kk], v1);          \
            v2 = fmaf(hc, w[2][kk], v2);          \
            v3 = fmaf(hc, w[3][kk], v3);
            FMA4(h.x, j * 4 + 0) FMA4(h.y, j * 4 + 1) FMA4(h.z, j * 4 + 2) FMA4(h.w, j * 4 + 3)
#undef FMA4
        }
        v0 = quad_sum(v0); v1 = quad_sum(v1); v2 = quad_sum(v2); v3 = quad_sum(v3);

        float fi = fsig(v0), ff = fsig(v1), fg = ftanh(v2), fo = fsig(v3);
        c = ff * c + fi * fg;
        float hn = fo * ftanh(c);
        if (p == 0) {
            hbuf[(t + 1) & 1][hidx(u)] = hn;
            hs[((size_t)t * BB + b) * HH + u] = f2bf(hn);
        }
        __syncthreads();
        xv = xn;
    }
}

// ---------------- FC head, LDS-transposed contiguous-row nontemporal stores ----------------
// block = (b, 256-wide n band); grid id = b*125 + nb so resident blocks
// concentrate in ~10 consecutive b slabs. Tile staged in LDS, then each wave
// stores 16 rows as full 1KB contiguous dwordx4 NT wave-stores (bypass L2 so
// the fw weight stream stays resident). t=0 zero row fused.
#define LDSW 260  // 256 + 4 pad dwords
__global__ __launch_bounds__(256) void fc_k(const unsigned short* __restrict__ hs,
                                            const unsigned short* __restrict__ fw,
                                            const float* __restrict__ fb,
                                            float* __restrict__ out) {
    int id = blockIdx.x;
    int b = id / 125;
    int nb = id % 125;
    int n0 = nb * 256;
    int wave = threadIdx.x >> 6;
    int lane = threadIdx.x & 63;
    int l15 = lane & 15;
    int kg = lane >> 4;

    __shared__ __align__(16) float lds[64 * LDSW];

    // B fragments (hs row b): B[N = t = ts*16+l15][K = kt*32 + kg*8 + j]
    bf16x8 bfr[4][4];
#pragma unroll
    for (int ts = 0; ts < 4; ++ts) {
        int t = ts * 16 + l15;
        int tc = t > 62 ? 62 : t;  // row 63 garbage, never stored
        const unsigned short* ph = hs + ((size_t)tc * BB + b) * HH + kg * 8;
#pragma unroll
        for (int kt = 0; kt < 4; ++kt) bfr[ts][kt] = *(const bf16x8*)(ph + kt * 32);
    }

    // compute 4 n-subtiles (ns) x 4 t-subtiles per wave, dump to LDS
#pragma unroll
    for (int i = 0; i < 4; ++i) {
        int ns = wave * 4 + i;                       // n subtile 0..15
        const unsigned short* arow = fw + (size_t)(n0 + ns * 16 + l15) * HH + kg * 8;
        bf16x8 a[4];
#pragma unroll
        for (int kt = 0; kt < 4; ++kt) a[kt] = *(const bf16x8*)(arow + kt * 32);

        f32x4 ac0 = (f32x4){0.f, 0.f, 0.f, 0.f};
        f32x4 ac1 = (f32x4){0.f, 0.f, 0.f, 0.f};
        f32x4 ac2 = (f32x4){0.f, 0.f, 0.f, 0.f};
        f32x4 ac3 = (f32x4){0.f, 0.f, 0.f, 0.f};
#pragma unroll
        for (int kt = 0; kt < 4; ++kt) {
            ac0 = __builtin_amdgcn_mfma_f32_16x16x32_bf16(a[kt], bfr[0][kt], ac0, 0, 0, 0);
            ac1 = __builtin_amdgcn_mfma_f32_16x16x32_bf16(a[kt], bfr[1][kt], ac1, 0, 0, 0);
            ac2 = __builtin_amdgcn_mfma_f32_16x16x32_bf16(a[kt], bfr[2][kt], ac2, 0, 0, 0);
            ac3 = __builtin_amdgcn_mfma_f32_16x16x32_bf16(a[kt], bfr[3][kt], ac3, 0, 0, 0);
        }
        // D: lane l15 -> t (N), regs j -> n offset kg*4+j (M)
        int nc = ns * 16 + kg * 4;
#define DUMP(ts, accv)                                                         \
        *(f32x4*)(&lds[(ts * 16 + l15) * LDSW + nc]) = accv;
        DUMP(0, ac0) DUMP(1, ac1) DUMP(2, ac2) DUMP(3, ac3)
#undef DUMP
    }
    __syncthreads();

    // store phase: wave w -> out rows t = w*16 .. w*16+15, 1KB contiguous each
    float4 biasv = *(const float4*)(fb + n0 + lane * 4);
    size_t outb = (size_t)b * TTOT * VOUT + n0 + lane * 4;
#pragma unroll
    for (int r = 0; r < 16; ++r) {
        int ot = wave * 16 + r;
        f32x4 v;
        if (ot == 0) {
            v = (f32x4){0.f, 0.f, 0.f, 0.f};
        } else {
            f32x4 s = *(const f32x4*)(&lds[(ot - 1) * LDSW + lane * 4]);
            v[0] = s[0] + biasv.x; v[1] = s[1] + biasv.y; v[2] = s[2] + biasv.z; v[3] = s[3] + biasv.w;
        }
        __builtin_nontemporal_store(v, (f32x4*)(out + outb + (size_t)ot * VOUT));
    }
}

extern "C" void kernel_launch(void* const* d_in, const int* in_sizes, int n_in,
                              void* d_out, int out_size, void* d_ws, size_t ws_size,
                              hipStream_t stream) {
    const int* src = (const int*)d_in[0];
    const int* tgt = (const int*)d_in[1];
    const float* enc_emb = (const float*)d_in[2];
    const float* dec_emb = (const float*)d_in[3];
    const float* enc_Wih = (const float*)d_in[4];
    const float* enc_Whh = (const float*)d_in[5];
    const float* enc_bih = (const float*)d_in[6];
    const float* enc_bhh = (const float*)d_in[7];
    const float* dec_Wih = (const float*)d_in[8];
    const float* dec_Whh = (const float*)d_in[9];
    const float* dec_bih = (const float*)d_in[10];
    const float* dec_bhh = (const float*)d_in[11];
    const float* fc_W = (const float*)d_in[12];
    const float* fc_b = (const float*)d_in[13];
    float* out = (float*)d_out;
    char* ws = (char*)d_ws;

    // workspace layout (bytes)
    float* table = (float*)(ws + 0);                        // 256*512*4   = 524288
    unsigned short* hs = (unsigned short*)(ws + 589824);    // 63*64*128*2 = 1032192
    unsigned short* fwb = (unsigned short*)(ws + 1622016);  // 32000*128*2 = 8192000
    float* xgd = (float*)(ws + 9814016);                    // 63*64*512*4 = 8257536
    // total 18071552 bytes

    enc_table_k<<<VIN, 512, 0, stream>>>(enc_emb, enc_Wih, enc_bih, table);
    xg_dec_k<<<(63 * 64) / 8, 512, 0, stream>>>(tgt, dec_emb, dec_Wih, dec_bih, xgd);
    conv_bf16<<<(VOUT * HH / 4 + 255) / 256, 256, 0, stream>>>(fc_W, fwb, VOUT * HH / 4);
    lstm_k<<<BB, 512, 0, stream>>>(table, src, enc_Whh, enc_bhh, xgd, dec_Whh, dec_bhh, hs);
    fc_k<<<64 * 125, 256, 0, stream>>>(hs, fwb, fc_b, out);
}